// Round 2
// baseline (2535.239 us; speedup 1.0000x reference)
//
#include <hip/hip_runtime.h>

#define NN 10000
#define NE 160000

// ---------------------------------------------------------------------------
// Workspace layout (floats):
//   qkv1 : NN*1536   (q cols 0-511 | k 512-1023 | v 1024-1535), row stride 1536
//   h1   : NN*512    (init = skip GEMM, += attention messages, then ReLU)
//   ex1  : NE*4      (exp(logit) per edge/head; reused for layer 2)
//   den1 : NN*4
//   qkv2 : NN*12     (q2 0-3 | k2 4-7 | v2 8-11), row stride 12
//   acc2 : NN*4      (init = skip2, += messages2)
//   den2 : NN*4
// total ~ 85.4 MB
// ---------------------------------------------------------------------------

struct Seg { const float* W; const float* b; float* out; int ld; };

// C[64 x 64 tile] = A[M x 128] * W[512 x 128]^T + b, XOR-swizzled LDS (64KB)
__global__ __launch_bounds__(256) void gemm_l1(
    const float* __restrict__ A, Seg s0, Seg s1, Seg s2, Seg s3)
{
  __shared__ float As[64][128];
  __shared__ float Bs[64][128];
  const int by = blockIdx.y;            // 0..31 (4 segs * 8 col-tiles)
  const int seg = by >> 3;
  const int colInSeg = (by & 7) << 6;
  Seg sg = (seg == 0) ? s0 : (seg == 1) ? s1 : (seg == 2) ? s2 : s3;
  const int row0 = blockIdx.x << 6;
  const int tid = threadIdx.x;

  // stage A (64 rows x 128) and B (64 W-rows x 128), swizzle: k4 ^= (row>>2)&7
  #pragma unroll
  for (int i = 0; i < 8; ++i) {
    int f = tid + (i << 8);
    int r = f >> 5, k4 = f & 31;
    int sw = (k4 ^ ((r >> 2) & 7)) << 2;
    float4 av = make_float4(0.f, 0.f, 0.f, 0.f);
    if (row0 + r < NN)
      av = *(const float4*)(A + (size_t)(row0 + r) * 128 + (k4 << 2));
    *(float4*)(&As[r][sw]) = av;
    float4 bv = *(const float4*)(sg.W + (size_t)(colInSeg + r) * 128 + (k4 << 2));
    *(float4*)(&Bs[r][sw]) = bv;
  }
  __syncthreads();

  const int tc = tid & 15, tr = tid >> 4;
  float acc[4][4] = {};
  #pragma unroll 8
  for (int k4 = 0; k4 < 32; ++k4) {
    float4 a[4], b[4];
    #pragma unroll
    for (int r = 0; r < 4; ++r)
      a[r] = *(const float4*)(&As[tr * 4 + r][(k4 ^ (tr & 7)) << 2]);
    #pragma unroll
    for (int c = 0; c < 4; ++c)
      b[c] = *(const float4*)(&Bs[tc * 4 + c][(k4 ^ (tc & 7)) << 2]);
    #pragma unroll
    for (int r = 0; r < 4; ++r)
      #pragma unroll
      for (int c = 0; c < 4; ++c)
        acc[r][c] += a[r].x * b[c].x + a[r].y * b[c].y
                   + a[r].z * b[c].z + a[r].w * b[c].w;
  }

  #pragma unroll
  for (int r = 0; r < 4; ++r) {
    int row = row0 + tr * 4 + r;
    if (row >= NN) continue;
    int col = colInSeg + (tc << 2);
    float4 o;
    o.x = acc[r][0] + sg.b[col + 0];
    o.y = acc[r][1] + sg.b[col + 1];
    o.z = acc[r][2] + sg.b[col + 2];
    o.w = acc[r][3] + sg.b[col + 3];
    *(float4*)(sg.out + (size_t)row * sg.ld + col) = o;
  }
}

// one wave per edge; lane = h*16 + cgroup; 128-dot per head via 16-lane reduce
__global__ __launch_bounds__(256) void edge_logits1(
    const float* __restrict__ qkv, const int* __restrict__ src,
    const int* __restrict__ dst, float* __restrict__ ex,
    float* __restrict__ den, int E)
{
  int e = blockIdx.x * 4 + (threadIdx.x >> 6);
  if (e >= E) return;
  int lane = threadIdx.x & 63;
  int h = lane >> 4, c0 = (lane & 15) << 3;
  int s = src[e], d = dst[e];
  const float* q = qkv + (size_t)d * 1536 + h * 128 + c0;
  const float* k = qkv + (size_t)s * 1536 + 512 + h * 128 + c0;
  float4 q0 = *(const float4*)q, q1 = *(const float4*)(q + 4);
  float4 k0 = *(const float4*)k, k1 = *(const float4*)(k + 4);
  float t = q0.x * k0.x + q0.y * k0.y + q0.z * k0.z + q0.w * k0.w
          + q1.x * k1.x + q1.y * k1.y + q1.z * k1.z + q1.w * k1.w;
  t += __shfl_xor(t, 1);
  t += __shfl_xor(t, 2);
  t += __shfl_xor(t, 4);
  t += __shfl_xor(t, 8);
  if ((lane & 15) == 0) {
    float v = __expf(t * 0.08838834764831845f);   // 1/sqrt(128)
    ex[e * 4 + h] = v;
    unsafeAtomicAdd(&den[d * 4 + h], v);
  }
}

__global__ __launch_bounds__(256) void edge_msg1(
    const float* __restrict__ qkv, const int* __restrict__ src,
    const int* __restrict__ dst, const float* __restrict__ ex,
    const float* __restrict__ den, float* __restrict__ h1, int E)
{
  int e = blockIdx.x * 4 + (threadIdx.x >> 6);
  if (e >= E) return;
  int lane = threadIdx.x & 63;
  int h = lane >> 4, c0 = (lane & 15) << 3;
  int s = src[e], d = dst[e];
  float alpha = ex[e * 4 + h] / fmaxf(den[d * 4 + h], 1e-16f);
  const float* v = qkv + (size_t)s * 1536 + 1024 + h * 128 + c0;
  float4 v0 = *(const float4*)v, v1 = *(const float4*)(v + 4);
  float* o = h1 + (size_t)d * 512 + h * 128 + c0;
  unsafeAtomicAdd(o + 0, alpha * v0.x);
  unsafeAtomicAdd(o + 1, alpha * v0.y);
  unsafeAtomicAdd(o + 2, alpha * v0.z);
  unsafeAtomicAdd(o + 3, alpha * v0.w);
  unsafeAtomicAdd(o + 4, alpha * v1.x);
  unsafeAtomicAdd(o + 5, alpha * v1.y);
  unsafeAtomicAdd(o + 6, alpha * v1.z);
  unsafeAtomicAdd(o + 7, alpha * v1.w);
}

__global__ __launch_bounds__(256) void relu_k(float* __restrict__ p, int n4)
{
  int i = blockIdx.x * 256 + threadIdx.x;
  int stride = gridDim.x * 256;
  for (; i < n4; i += stride) {
    float4 v = ((float4*)p)[i];
    v.x = fmaxf(v.x, 0.f); v.y = fmaxf(v.y, 0.f);
    v.z = fmaxf(v.z, 0.f); v.w = fmaxf(v.w, 0.f);
    ((float4*)p)[i] = v;
  }
}

// layer-2 projections: 16 outputs per node, each a 512-dot
__global__ __launch_bounds__(256) void gemm_l2(
    const float* __restrict__ h1,
    const float* __restrict__ Wq, const float* __restrict__ bq,
    const float* __restrict__ Wk, const float* __restrict__ bk,
    const float* __restrict__ Wv, const float* __restrict__ bv,
    const float* __restrict__ Ws, const float* __restrict__ bs,
    float* __restrict__ qkv2, float* __restrict__ acc2)
{
  int t = blockIdx.x * 256 + threadIdx.x;
  if (t >= NN * 16) return;
  int n = t >> 4, j = t & 15;
  int sg = j >> 2, r = j & 3;
  const float* W = (sg == 0) ? Wq : (sg == 1) ? Wk : (sg == 2) ? Wv : Ws;
  const float* b = (sg == 0) ? bq : (sg == 1) ? bk : (sg == 2) ? bv : bs;
  const float* a = h1 + (size_t)n * 512;
  const float* w = W + (size_t)r * 512;
  float s = 0.f;
  #pragma unroll 8
  for (int i = 0; i < 128; ++i) {
    float4 av = ((const float4*)a)[i];
    float4 wv = ((const float4*)w)[i];
    s += av.x * wv.x + av.y * wv.y + av.z * wv.z + av.w * wv.w;
  }
  s += b[r];
  if (sg < 3) qkv2[n * 12 + sg * 4 + r] = s;
  else        acc2[n * 4 + r] = s;
}

__global__ __launch_bounds__(256) void edge2_logits(
    const float* __restrict__ qkv2, const int* __restrict__ src,
    const int* __restrict__ dst, float* __restrict__ ex,
    float* __restrict__ den, int E)
{
  int e = blockIdx.x * 256 + threadIdx.x;
  if (e >= E) return;
  int s = src[e], d = dst[e];
  float4 q = *(const float4*)(qkv2 + (size_t)d * 12);
  float4 k = *(const float4*)(qkv2 + (size_t)s * 12 + 4);
  float4 exv;
  exv.x = __expf(q.x * k.x);
  exv.y = __expf(q.y * k.y);
  exv.z = __expf(q.z * k.z);
  exv.w = __expf(q.w * k.w);
  *(float4*)(ex + (size_t)e * 4) = exv;
  unsafeAtomicAdd(&den[d * 4 + 0], exv.x);
  unsafeAtomicAdd(&den[d * 4 + 1], exv.y);
  unsafeAtomicAdd(&den[d * 4 + 2], exv.z);
  unsafeAtomicAdd(&den[d * 4 + 3], exv.w);
}

__global__ __launch_bounds__(256) void edge2_msg(
    const float* __restrict__ qkv2, const int* __restrict__ src,
    const int* __restrict__ dst, const float* __restrict__ ex,
    const float* __restrict__ den, float* __restrict__ acc2, int E)
{
  int e = blockIdx.x * 256 + threadIdx.x;
  if (e >= E) return;
  int s = src[e], d = dst[e];
  float4 exv = *(const float4*)(ex + (size_t)e * 4);
  float4 v = *(const float4*)(qkv2 + (size_t)s * 12 + 8);
  float4 dn = *(const float4*)(den + (size_t)d * 4);
  unsafeAtomicAdd(&acc2[d * 4 + 0], exv.x / fmaxf(dn.x, 1e-16f) * v.x);
  unsafeAtomicAdd(&acc2[d * 4 + 1], exv.y / fmaxf(dn.y, 1e-16f) * v.y);
  unsafeAtomicAdd(&acc2[d * 4 + 2], exv.z / fmaxf(dn.z, 1e-16f) * v.z);
  unsafeAtomicAdd(&acc2[d * 4 + 3], exv.w / fmaxf(dn.w, 1e-16f) * v.w);
}

__global__ void out_init(float* __restrict__ out, const float* __restrict__ bl)
{
  out[0] = bl[0];
}

__global__ __launch_bounds__(256) void final_reduce(
    const float* __restrict__ acc2, const float* __restrict__ Wl,
    float* __restrict__ out)
{
  __shared__ float red[256];
  float w0 = Wl[0], w1 = Wl[1], w2 = Wl[2], w3 = Wl[3];
  float s = 0.f;
  for (int n = blockIdx.x * 256 + threadIdx.x; n < NN; n += gridDim.x * 256) {
    float4 a = *(const float4*)(acc2 + (size_t)n * 4);
    s += a.x * w0 + a.y * w1 + a.z * w2 + a.w * w3;
  }
  red[threadIdx.x] = s;
  __syncthreads();
  for (int off = 128; off; off >>= 1) {
    if (threadIdx.x < off) red[threadIdx.x] += red[threadIdx.x + off];
    __syncthreads();
  }
  if (threadIdx.x == 0) unsafeAtomicAdd(out, red[0] * (1.0f / NN));
}

extern "C" void kernel_launch(void* const* d_in, const int* in_sizes, int n_in,
                              void* d_out, int out_size, void* d_ws, size_t ws_size,
                              hipStream_t stream)
{
  const float* x   = (const float*)d_in[0];
  const int*   ei  = (const int*)d_in[1];
  const float *Wq1 = (const float*)d_in[2],  *bq1 = (const float*)d_in[3];
  const float *Wk1 = (const float*)d_in[4],  *bk1 = (const float*)d_in[5];
  const float *Wv1 = (const float*)d_in[6],  *bv1 = (const float*)d_in[7];
  const float *Ws1 = (const float*)d_in[8],  *bs1 = (const float*)d_in[9];
  const float *Wq2 = (const float*)d_in[10], *bq2 = (const float*)d_in[11];
  const float *Wk2 = (const float*)d_in[12], *bk2 = (const float*)d_in[13];
  const float *Wv2 = (const float*)d_in[14], *bv2 = (const float*)d_in[15];
  const float *Ws2 = (const float*)d_in[16], *bs2 = (const float*)d_in[17];
  const float *Wl  = (const float*)d_in[18], *bl  = (const float*)d_in[19];
  const int* srcp = ei;
  const int* dstp = ei + NE;

  float* ws   = (float*)d_ws;
  float* qkv1 = ws;                               // NN*1536
  float* h1   = qkv1 + (size_t)NN * 1536;         // NN*512
  float* ex1  = h1 + (size_t)NN * 512;            // NE*4
  float* den1 = ex1 + (size_t)NE * 4;             // NN*4
  float* qkv2 = den1 + (size_t)NN * 4;            // NN*12
  float* acc2 = qkv2 + (size_t)NN * 12;           // NN*4
  float* den2 = acc2 + (size_t)NN * 4;            // NN*4

  hipMemsetAsync(den1, 0, (size_t)NN * 4 * sizeof(float), stream);
  hipMemsetAsync(den2, 0, (size_t)NN * 4 * sizeof(float), stream);

  {
    Seg s0{Wq1, bq1, qkv1 + 0,    1536};
    Seg s1{Wk1, bk1, qkv1 + 512,  1536};
    Seg s2{Wv1, bv1, qkv1 + 1024, 1536};
    Seg s3{Ws1, bs1, h1,          512};
    dim3 grid((NN + 63) / 64, 32);
    gemm_l1<<<grid, 256, 0, stream>>>(x, s0, s1, s2, s3);
  }

  edge_logits1<<<(NE + 3) / 4, 256, 0, stream>>>(qkv1, srcp, dstp, ex1, den1, NE);
  edge_msg1<<<(NE + 3) / 4, 256, 0, stream>>>(qkv1, srcp, dstp, ex1, den1, h1, NE);
  relu_k<<<1024, 256, 0, stream>>>(h1, NN * 512 / 4);
  gemm_l2<<<(NN * 16 + 255) / 256, 256, 0, stream>>>(
      h1, Wq2, bq2, Wk2, bk2, Wv2, bv2, Ws2, bs2, qkv2, acc2);
  edge2_logits<<<(NE + 255) / 256, 256, 0, stream>>>(qkv2, srcp, dstp, ex1, den2, NE);
  edge2_msg<<<(NE + 255) / 256, 256, 0, stream>>>(qkv2, srcp, dstp, ex1, den2, acc2, NE);
  out_init<<<1, 1, 0, stream>>>((float*)d_out, bl);
  final_reduce<<<40, 256, 0, stream>>>(acc2, Wl, (float*)d_out);
}

// Round 3
// 322.555 us; speedup vs baseline: 7.8599x; 7.8599x over previous
//
#include <hip/hip_runtime.h>

#define NN 10000
#define NE 160000

// ---------------------------------------------------------------------------
// Workspace layout:
//   floats:
//     qkv1 : NN*1536   (q 0-511 | k 512-1023 | v 1024-1535), row stride 1536
//     h1   : NN*512    (gemm_l1 writes skip; attn1 rewrites relu(skip+attn))
//     qkv2 : NN*12     (q2 0-3 | k2 4-7 | v2 8-11)
//     acc2 : NN*4      (gemm_l2 writes skip2; attn2 += attention out)
//   ints (after floats):
//     deg     : NN
//     rowptr  : NN+1
//     cursor  : NN
//     csr_src : NE     (src node ids grouped by dst)
// ---------------------------------------------------------------------------

struct Seg { const float* W; const float* b; float* out; int ld; };

// C[64 x 64 tile] = A[M x 128] * W[512 x 128]^T + b, XOR-swizzled LDS
__global__ __launch_bounds__(256) void gemm_l1(
    const float* __restrict__ A, Seg s0, Seg s1, Seg s2, Seg s3)
{
  __shared__ float As[64][128];
  __shared__ float Bs[64][128];
  const int by = blockIdx.y;            // 0..31 (4 segs * 8 col-tiles)
  const int seg = by >> 3;
  const int colInSeg = (by & 7) << 6;
  Seg sg = (seg == 0) ? s0 : (seg == 1) ? s1 : (seg == 2) ? s2 : s3;
  const int row0 = blockIdx.x << 6;
  const int tid = threadIdx.x;

  #pragma unroll
  for (int i = 0; i < 8; ++i) {
    int f = tid + (i << 8);
    int r = f >> 5, k4 = f & 31;
    int sw = (k4 ^ ((r >> 2) & 7)) << 2;
    float4 av = make_float4(0.f, 0.f, 0.f, 0.f);
    if (row0 + r < NN)
      av = *(const float4*)(A + (size_t)(row0 + r) * 128 + (k4 << 2));
    *(float4*)(&As[r][sw]) = av;
    float4 bv = *(const float4*)(sg.W + (size_t)(colInSeg + r) * 128 + (k4 << 2));
    *(float4*)(&Bs[r][sw]) = bv;
  }
  __syncthreads();

  const int tc = tid & 15, tr = tid >> 4;
  float acc[4][4] = {};
  #pragma unroll 8
  for (int k4 = 0; k4 < 32; ++k4) {
    float4 a[4], b[4];
    #pragma unroll
    for (int r = 0; r < 4; ++r)
      a[r] = *(const float4*)(&As[tr * 4 + r][(k4 ^ (tr & 7)) << 2]);
    #pragma unroll
    for (int c = 0; c < 4; ++c)
      b[c] = *(const float4*)(&Bs[tc * 4 + c][(k4 ^ (tc & 7)) << 2]);
    #pragma unroll
    for (int r = 0; r < 4; ++r)
      #pragma unroll
      for (int c = 0; c < 4; ++c)
        acc[r][c] += a[r].x * b[c].x + a[r].y * b[c].y
                   + a[r].z * b[c].z + a[r].w * b[c].w;
  }

  #pragma unroll
  for (int r = 0; r < 4; ++r) {
    int row = row0 + tr * 4 + r;
    if (row >= NN) continue;
    int col = colInSeg + (tc << 2);
    float4 o;
    o.x = acc[r][0] + sg.b[col + 0];
    o.y = acc[r][1] + sg.b[col + 1];
    o.z = acc[r][2] + sg.b[col + 2];
    o.w = acc[r][3] + sg.b[col + 3];
    *(float4*)(sg.out + (size_t)row * sg.ld + col) = o;
  }
}

// ---- CSR build ------------------------------------------------------------

__global__ __launch_bounds__(256) void count_deg(
    const int* __restrict__ dst, int* __restrict__ deg, int E)
{
  int e = blockIdx.x * 256 + threadIdx.x;
  if (e < E) atomicAdd(&deg[dst[e]], 1);
}

__global__ __launch_bounds__(1024) void scan_k(
    const int* __restrict__ deg, int* __restrict__ rowptr,
    int* __restrict__ cursor)
{
  __shared__ int part[1024];
  int tid = threadIdx.x;
  int base = tid * 10;
  int loc[10]; int s = 0;
  #pragma unroll
  for (int i = 0; i < 10; ++i) {
    int v = (base + i < NN) ? deg[base + i] : 0;
    loc[i] = s; s += v;
  }
  part[tid] = s;
  __syncthreads();
  for (int off = 1; off < 1024; off <<= 1) {
    int v = (tid >= off) ? part[tid - off] : 0;
    __syncthreads();
    part[tid] += v;
    __syncthreads();
  }
  int prev = (tid == 0) ? 0 : part[tid - 1];
  #pragma unroll
  for (int i = 0; i < 10; ++i) {
    int idx = base + i;
    if (idx < NN) { int r = prev + loc[i]; rowptr[idx] = r; cursor[idx] = r; }
  }
  if (tid == 1023) rowptr[NN] = part[1023];
}

__global__ __launch_bounds__(256) void scatter_k(
    const int* __restrict__ src, const int* __restrict__ dst,
    int* __restrict__ cursor, int* __restrict__ csr_src, int E)
{
  int e = blockIdx.x * 256 + threadIdx.x;
  if (e >= E) return;
  int pos = atomicAdd(&cursor[dst[e]], 1);
  csr_src[pos] = src[e];
}

// ---- fused layer-1 attention: one wave per node ---------------------------
// lane = h*16 + cg; each lane owns 8 channels of head h.
// single pass: den += ex, acc += ex*v; out = relu(skip + acc/den)
__global__ __launch_bounds__(256) void attn1(
    const float* __restrict__ qkv, const int* __restrict__ rowptr,
    const int* __restrict__ csr_src, float* __restrict__ h1)
{
  int n = blockIdx.x * 4 + (threadIdx.x >> 6);
  if (n >= NN) return;
  int lane = threadIdx.x & 63;
  int h = lane >> 4, c0 = (lane & 15) << 3;
  const float* qp = qkv + (size_t)n * 1536 + h * 128 + c0;
  float4 q0 = *(const float4*)qp, q1 = *(const float4*)(qp + 4);
  float acc[8] = {};
  float den = 0.f;
  int e1 = rowptr[n + 1];
  for (int j = rowptr[n]; j < e1; ++j) {
    int s = csr_src[j];
    const float* kp = qkv + (size_t)s * 1536 + 512 + h * 128 + c0;
    float4 k0 = *(const float4*)kp, k1 = *(const float4*)(kp + 4);
    const float* vp = qkv + (size_t)s * 1536 + 1024 + h * 128 + c0;
    float4 v0 = *(const float4*)vp, v1 = *(const float4*)(vp + 4);
    float t = q0.x * k0.x + q0.y * k0.y + q0.z * k0.z + q0.w * k0.w
            + q1.x * k1.x + q1.y * k1.y + q1.z * k1.z + q1.w * k1.w;
    t += __shfl_xor(t, 1);
    t += __shfl_xor(t, 2);
    t += __shfl_xor(t, 4);
    t += __shfl_xor(t, 8);
    float ex = __expf(t * 0.08838834764831845f);   // 1/sqrt(128)
    den += ex;
    acc[0] += ex * v0.x; acc[1] += ex * v0.y;
    acc[2] += ex * v0.z; acc[3] += ex * v0.w;
    acc[4] += ex * v1.x; acc[5] += ex * v1.y;
    acc[6] += ex * v1.z; acc[7] += ex * v1.w;
  }
  float inv = 1.f / fmaxf(den, 1e-16f);
  float* op = h1 + (size_t)n * 512 + h * 128 + c0;
  float4 s0 = *(const float4*)op, s1 = *(const float4*)(op + 4);
  float4 o0, o1;
  o0.x = fmaxf(s0.x + acc[0] * inv, 0.f);
  o0.y = fmaxf(s0.y + acc[1] * inv, 0.f);
  o0.z = fmaxf(s0.z + acc[2] * inv, 0.f);
  o0.w = fmaxf(s0.w + acc[3] * inv, 0.f);
  o1.x = fmaxf(s1.x + acc[4] * inv, 0.f);
  o1.y = fmaxf(s1.y + acc[5] * inv, 0.f);
  o1.z = fmaxf(s1.z + acc[6] * inv, 0.f);
  o1.w = fmaxf(s1.w + acc[7] * inv, 0.f);
  *(float4*)op = o0;
  *(float4*)(op + 4) = o1;
}

// layer-2 projections: 16 outputs per node, each a 512-dot
__global__ __launch_bounds__(256) void gemm_l2(
    const float* __restrict__ h1,
    const float* __restrict__ Wq, const float* __restrict__ bq,
    const float* __restrict__ Wk, const float* __restrict__ bk,
    const float* __restrict__ Wv, const float* __restrict__ bv,
    const float* __restrict__ Ws, const float* __restrict__ bs,
    float* __restrict__ qkv2, float* __restrict__ acc2)
{
  int t = blockIdx.x * 256 + threadIdx.x;
  if (t >= NN * 16) return;
  int n = t >> 4, j = t & 15;
  int sg = j >> 2, r = j & 3;
  const float* W = (sg == 0) ? Wq : (sg == 1) ? Wk : (sg == 2) ? Wv : Ws;
  const float* b = (sg == 0) ? bq : (sg == 1) ? bk : (sg == 2) ? bv : bs;
  const float* a = h1 + (size_t)n * 512;
  const float* w = W + (size_t)r * 512;
  float s = 0.f;
  #pragma unroll 8
  for (int i = 0; i < 128; ++i) {
    float4 av = ((const float4*)a)[i];
    float4 wv = ((const float4*)w)[i];
    s += av.x * wv.x + av.y * wv.y + av.z * wv.z + av.w * wv.w;
  }
  s += b[r];
  if (sg < 3) qkv2[n * 12 + sg * 4 + r] = s;
  else        acc2[n * 4 + r] = s;
}

// fused layer-2 attention: one thread per (node, head)
__global__ __launch_bounds__(256) void attn2(
    const float* __restrict__ qkv2, const int* __restrict__ rowptr,
    const int* __restrict__ csr_src, float* __restrict__ acc2)
{
  int t = blockIdx.x * 256 + threadIdx.x;
  if (t >= NN * 4) return;
  int n = t >> 2, h = t & 3;
  float q = qkv2[n * 12 + h];
  float den = 0.f, acc = 0.f;
  int e1 = rowptr[n + 1];
  for (int j = rowptr[n]; j < e1; ++j) {
    int s = csr_src[j];
    float k = qkv2[s * 12 + 4 + h];
    float v = qkv2[s * 12 + 8 + h];
    float ex = __expf(q * k);
    den += ex; acc += ex * v;
  }
  acc2[t] += acc / fmaxf(den, 1e-16f);
}

__global__ void out_init(float* __restrict__ out, const float* __restrict__ bl)
{
  out[0] = bl[0];
}

__global__ __launch_bounds__(256) void final_reduce(
    const float* __restrict__ acc2, const float* __restrict__ Wl,
    float* __restrict__ out)
{
  __shared__ float red[256];
  float w0 = Wl[0], w1 = Wl[1], w2 = Wl[2], w3 = Wl[3];
  float s = 0.f;
  for (int n = blockIdx.x * 256 + threadIdx.x; n < NN; n += gridDim.x * 256) {
    float4 a = *(const float4*)(acc2 + (size_t)n * 4);
    s += a.x * w0 + a.y * w1 + a.z * w2 + a.w * w3;
  }
  red[threadIdx.x] = s;
  __syncthreads();
  for (int off = 128; off; off >>= 1) {
    if (threadIdx.x < off) red[threadIdx.x] += red[threadIdx.x + off];
    __syncthreads();
  }
  if (threadIdx.x == 0) unsafeAtomicAdd(out, red[0] * (1.0f / NN));
}

extern "C" void kernel_launch(void* const* d_in, const int* in_sizes, int n_in,
                              void* d_out, int out_size, void* d_ws, size_t ws_size,
                              hipStream_t stream)
{
  const float* x   = (const float*)d_in[0];
  const int*   ei  = (const int*)d_in[1];
  const float *Wq1 = (const float*)d_in[2],  *bq1 = (const float*)d_in[3];
  const float *Wk1 = (const float*)d_in[4],  *bk1 = (const float*)d_in[5];
  const float *Wv1 = (const float*)d_in[6],  *bv1 = (const float*)d_in[7];
  const float *Ws1 = (const float*)d_in[8],  *bs1 = (const float*)d_in[9];
  const float *Wq2 = (const float*)d_in[10], *bq2 = (const float*)d_in[11];
  const float *Wk2 = (const float*)d_in[12], *bk2 = (const float*)d_in[13];
  const float *Wv2 = (const float*)d_in[14], *bv2 = (const float*)d_in[15];
  const float *Ws2 = (const float*)d_in[16], *bs2 = (const float*)d_in[17];
  const float *Wl  = (const float*)d_in[18], *bl  = (const float*)d_in[19];
  const int* srcp = ei;
  const int* dstp = ei + NE;

  float* ws   = (float*)d_ws;
  float* qkv1 = ws;                               // NN*1536
  float* h1   = qkv1 + (size_t)NN * 1536;         // NN*512
  float* qkv2 = h1 + (size_t)NN * 512;            // NN*12
  float* acc2 = qkv2 + (size_t)NN * 12;           // NN*4
  int*   deg     = (int*)(acc2 + (size_t)NN * 4); // NN
  int*   rowptr  = deg + NN;                      // NN+1
  int*   cursor  = rowptr + NN + 1;               // NN
  int*   csr_src = cursor + NN;                   // NE

  // CSR build
  hipMemsetAsync(deg, 0, (size_t)NN * sizeof(int), stream);
  count_deg<<<(NE + 255) / 256, 256, 0, stream>>>(dstp, deg, NE);
  scan_k<<<1, 1024, 0, stream>>>(deg, rowptr, cursor);
  scatter_k<<<(NE + 255) / 256, 256, 0, stream>>>(srcp, dstp, cursor, csr_src, NE);

  // layer-1 projections (q,k,v into qkv1; skip into h1)
  {
    Seg s0{Wq1, bq1, qkv1 + 0,    1536};
    Seg s1{Wk1, bk1, qkv1 + 512,  1536};
    Seg s2{Wv1, bv1, qkv1 + 1024, 1536};
    Seg s3{Ws1, bs1, h1,          512};
    dim3 grid((NN + 63) / 64, 32);
    gemm_l1<<<grid, 256, 0, stream>>>(x, s0, s1, s2, s3);
  }

  attn1<<<(NN + 3) / 4, 256, 0, stream>>>(qkv1, rowptr, csr_src, h1);
  gemm_l2<<<(NN * 16 + 255) / 256, 256, 0, stream>>>(
      h1, Wq2, bq2, Wk2, bk2, Wv2, bv2, Ws2, bs2, qkv2, acc2);
  attn2<<<(NN * 4 + 255) / 256, 256, 0, stream>>>(qkv2, rowptr, csr_src, acc2);
  out_init<<<1, 1, 0, stream>>>((float*)d_out, bl);
  final_reduce<<<40, 256, 0, stream>>>(acc2, Wl, (float*)d_out);
}

// Round 4
// 186.817 us; speedup vs baseline: 13.5707x; 1.7266x over previous
//
#include <hip/hip_runtime.h>

#define NN 10000
#define NE 160000

typedef __attribute__((ext_vector_type(8))) short bf16x8;
typedef __attribute__((ext_vector_type(4))) float f32x4;

__device__ inline ushort f2bf(float x) {
  // round-to-nearest-even fp32 -> bf16
  uint u = __float_as_uint(x);
  return (ushort)((u + 0x7fffu + ((u >> 16) & 1u)) >> 16);
}

__device__ inline void unpack8(uint4 u, float* f) {
  f[0] = __uint_as_float(u.x << 16); f[1] = __uint_as_float(u.x & 0xffff0000u);
  f[2] = __uint_as_float(u.y << 16); f[3] = __uint_as_float(u.y & 0xffff0000u);
  f[4] = __uint_as_float(u.z << 16); f[5] = __uint_as_float(u.z & 0xffff0000u);
  f[6] = __uint_as_float(u.w << 16); f[7] = __uint_as_float(u.w & 0xffff0000u);
}

// ---- fp32 -> bf16 conversion (vectorized) ----------------------------------
__global__ __launch_bounds__(256) void f2bf_k(
    const float* __restrict__ in, ushort* __restrict__ out, int n4)
{
  int i = blockIdx.x * 256 + threadIdx.x;
  if (i >= n4) return;
  float4 v = ((const float4*)in)[i];
  ushort4 o;
  o.x = f2bf(v.x); o.y = f2bf(v.y); o.z = f2bf(v.z); o.w = f2bf(v.w);
  ((ushort4*)out)[i] = o;
}

// ---- layer-1 GEMM: [NN x 128] * [2048 x 128]^T via bf16 MFMA ---------------
// block = 256 thr (4 waves, 2x2), tile 128(M) x 64(N), K=128 in one LDS shot.
// LDS XOR-swizzle: 16B slot c within row r stored at c ^ (r & 7).
__global__ __launch_bounds__(256) void gemm_l1_mfma(
    const ushort* __restrict__ xbf,   // [NN][128] bf16
    const ushort* __restrict__ wbf,   // [2048][128] bf16 (Wq|Wk|Wv|Ws stacked)
    const float* __restrict__ bq, const float* __restrict__ bk,
    const float* __restrict__ bv, const float* __restrict__ bs,
    ushort* __restrict__ qkv1,        // [NN][1536] bf16 (q|k|v)
    float* __restrict__ h1)           // [NN][512] f32 (skip)
{
  __shared__ __align__(16) ushort Al[128 * 128];  // 32 KB
  __shared__ __align__(16) ushort Bl[64 * 128];   // 16 KB
  const int row0 = blockIdx.x << 7;
  const int ncol0 = blockIdx.y << 6;              // 0..2047
  const int tid = threadIdx.x;

  // stage A: 2048 slots of 16B
  #pragma unroll
  for (int i = 0; i < 8; ++i) {
    int slot = tid + (i << 8);
    int r = slot >> 4, c = slot & 15;
    int gr = row0 + r;
    uint4 v = make_uint4(0u, 0u, 0u, 0u);
    if (gr < NN) v = *(const uint4*)(xbf + (size_t)gr * 128 + (c << 3));
    *(uint4*)(Al + r * 128 + ((c ^ (r & 7)) << 3)) = v;
  }
  // stage B: 1024 slots
  #pragma unroll
  for (int i = 0; i < 4; ++i) {
    int slot = tid + (i << 8);
    int r = slot >> 4, c = slot & 15;
    uint4 v = *(const uint4*)(wbf + (size_t)(ncol0 + r) * 128 + (c << 3));
    *(uint4*)(Bl + r * 128 + ((c ^ (r & 7)) << 3)) = v;
  }
  __syncthreads();

  const int wid = tid >> 6, lane = tid & 63;
  const int wm = wid >> 1, wn = wid & 1;     // wave tile 64x32
  const int lr = lane & 15, lkg = lane >> 4; // frag row/col, k-group

  f32x4 acc[4][2];
  #pragma unroll
  for (int m = 0; m < 4; ++m)
    #pragma unroll
    for (int n = 0; n < 2; ++n) acc[m][n] = (f32x4){0.f, 0.f, 0.f, 0.f};

  #pragma unroll
  for (int ks = 0; ks < 4; ++ks) {
    int c16 = (ks << 2) + lkg;               // 16B slot within row
    bf16x8 a[4], b[2];
    #pragma unroll
    for (int mf = 0; mf < 4; ++mf) {
      int r = (wm << 6) + (mf << 4) + lr;
      a[mf] = *(const bf16x8*)(Al + r * 128 + ((c16 ^ (r & 7)) << 3));
    }
    #pragma unroll
    for (int nf = 0; nf < 2; ++nf) {
      int r = (wn << 5) + (nf << 4) + lr;
      b[nf] = *(const bf16x8*)(Bl + r * 128 + ((c16 ^ (r & 7)) << 3));
    }
    #pragma unroll
    for (int mf = 0; mf < 4; ++mf)
      #pragma unroll
      for (int nf = 0; nf < 2; ++nf)
        acc[mf][nf] = __builtin_amdgcn_mfma_f32_16x16x32_bf16(
            a[mf], b[nf], acc[mf][nf], 0, 0, 0);
  }

  const int seg = ncol0 >> 9;
  const int colInSeg = ncol0 & 511;
  const float* bias = (seg == 0) ? bq : (seg == 1) ? bk : (seg == 2) ? bv : bs;
  #pragma unroll
  for (int mf = 0; mf < 4; ++mf) {
    #pragma unroll
    for (int nf = 0; nf < 2; ++nf) {
      int col = colInSeg + (wn << 5) + (nf << 4) + lr;
      float bb = bias[col];
      #pragma unroll
      for (int r = 0; r < 4; ++r) {
        int row = row0 + (wm << 6) + (mf << 4) + (lkg << 2) + r;
        if (row >= NN) continue;
        float val = acc[mf][nf][r] + bb;
        if (seg < 3) qkv1[(size_t)row * 1536 + (seg << 9) + col] = f2bf(val);
        else         h1[(size_t)row * 512 + col] = val;
      }
    }
  }
}

// ---- CSR build ------------------------------------------------------------
__global__ __launch_bounds__(256) void count_deg(
    const int* __restrict__ dst, int* __restrict__ deg, int E)
{
  int e = blockIdx.x * 256 + threadIdx.x;
  if (e < E) atomicAdd(&deg[dst[e]], 1);
}

__global__ __launch_bounds__(1024) void scan_k(
    const int* __restrict__ deg, int* __restrict__ rowptr,
    int* __restrict__ cursor)
{
  __shared__ int part[1024];
  int tid = threadIdx.x;
  int base = tid * 10;
  int loc[10]; int s = 0;
  #pragma unroll
  for (int i = 0; i < 10; ++i) {
    int v = (base + i < NN) ? deg[base + i] : 0;
    loc[i] = s; s += v;
  }
  part[tid] = s;
  __syncthreads();
  for (int off = 1; off < 1024; off <<= 1) {
    int v = (tid >= off) ? part[tid - off] : 0;
    __syncthreads();
    part[tid] += v;
    __syncthreads();
  }
  int prev = (tid == 0) ? 0 : part[tid - 1];
  #pragma unroll
  for (int i = 0; i < 10; ++i) {
    int idx = base + i;
    if (idx < NN) { int r = prev + loc[i]; rowptr[idx] = r; cursor[idx] = r; }
  }
  if (tid == 1023) rowptr[NN] = part[1023];
}

__global__ __launch_bounds__(256) void scatter_k(
    const int* __restrict__ src, const int* __restrict__ dst,
    int* __restrict__ cursor, int* __restrict__ csr_src, int E)
{
  int e = blockIdx.x * 256 + threadIdx.x;
  if (e >= E) return;
  int pos = atomicAdd(&cursor[dst[e]], 1);
  csr_src[pos] = src[e];
}

// ---- fused layer-1 attention (bf16 gather): one wave per node --------------
__global__ __launch_bounds__(256) void attn1(
    const ushort* __restrict__ qkv, const int* __restrict__ rowptr,
    const int* __restrict__ csr_src, float* __restrict__ h1)
{
  int n = blockIdx.x * 4 + (threadIdx.x >> 6);
  if (n >= NN) return;
  int lane = threadIdx.x & 63;
  int h = lane >> 4, c0 = (lane & 15) << 3;
  float q[8];
  unpack8(*(const uint4*)(qkv + (size_t)n * 1536 + h * 128 + c0), q);
  float acc[8] = {};
  float den = 0.f;
  int e1 = rowptr[n + 1];
  for (int j = rowptr[n]; j < e1; ++j) {
    int s = csr_src[j];
    const ushort* base = qkv + (size_t)s * 1536 + h * 128 + c0;
    float k[8], v[8];
    unpack8(*(const uint4*)(base + 512), k);
    unpack8(*(const uint4*)(base + 1024), v);
    float t = q[0]*k[0] + q[1]*k[1] + q[2]*k[2] + q[3]*k[3]
            + q[4]*k[4] + q[5]*k[5] + q[6]*k[6] + q[7]*k[7];
    t += __shfl_xor(t, 1);
    t += __shfl_xor(t, 2);
    t += __shfl_xor(t, 4);
    t += __shfl_xor(t, 8);
    float ex = __expf(t * 0.08838834764831845f);   // 1/sqrt(128)
    den += ex;
    #pragma unroll
    for (int i = 0; i < 8; ++i) acc[i] += ex * v[i];
  }
  float inv = 1.f / fmaxf(den, 1e-16f);
  float* op = h1 + (size_t)n * 512 + h * 128 + c0;
  float4 s0 = *(const float4*)op, s1 = *(const float4*)(op + 4);
  float4 o0, o1;
  o0.x = fmaxf(s0.x + acc[0] * inv, 0.f);
  o0.y = fmaxf(s0.y + acc[1] * inv, 0.f);
  o0.z = fmaxf(s0.z + acc[2] * inv, 0.f);
  o0.w = fmaxf(s0.w + acc[3] * inv, 0.f);
  o1.x = fmaxf(s1.x + acc[4] * inv, 0.f);
  o1.y = fmaxf(s1.y + acc[5] * inv, 0.f);
  o1.z = fmaxf(s1.z + acc[6] * inv, 0.f);
  o1.w = fmaxf(s1.w + acc[7] * inv, 0.f);
  *(float4*)op = o0;
  *(float4*)(op + 4) = o1;
}

// ---- layer-2 projections: 64 nodes/block, wave w covers i in [w*128,w*128+128)
// W indices wave-uniform -> scalar loads; h1 read exactly once.
__global__ __launch_bounds__(256) void gemm_l2(
    const float* __restrict__ h1,
    const float* __restrict__ Wq, const float* __restrict__ bq,
    const float* __restrict__ Wk, const float* __restrict__ bk,
    const float* __restrict__ Wv, const float* __restrict__ bv,
    const float* __restrict__ Ws, const float* __restrict__ bs,
    float* __restrict__ qkv2, float* __restrict__ acc2)
{
  __shared__ float red[4][64][17];
  int n0 = blockIdx.x * 64;
  int wid = threadIdx.x >> 6, lane = threadIdx.x & 63;
  int n = n0 + lane;
  const float* Wm[4] = {Wq, Wk, Wv, Ws};
  float s[16] = {};
  if (n < NN) {
    const float* a = h1 + (size_t)n * 512 + wid * 128;
    #pragma unroll 4
    for (int i = 0; i < 128; i += 4) {
      float4 av = *(const float4*)(a + i);
      #pragma unroll
      for (int j = 0; j < 16; ++j) {
        const float* w = Wm[j >> 2] + (size_t)(j & 3) * 512 + wid * 128 + i;
        s[j] += av.x * w[0] + av.y * w[1] + av.z * w[2] + av.w * w[3];
      }
    }
  }
  #pragma unroll
  for (int j = 0; j < 16; ++j) red[wid][lane][j] = s[j];
  __syncthreads();
  #pragma unroll
  for (int q = 0; q < 4; ++q) {
    int idx = threadIdx.x * 4 + q;    // 0..1023
    int ln = idx >> 4, j = idx & 15;
    int nn2 = n0 + ln;
    if (nn2 >= NN) continue;
    float v = red[0][ln][j] + red[1][ln][j] + red[2][ln][j] + red[3][ln][j];
    int sg = j >> 2, r = j & 3;
    const float* bb = (sg == 0) ? bq : (sg == 1) ? bk : (sg == 2) ? bv : bs;
    v += bb[r];
    if (sg < 3) qkv2[nn2 * 12 + sg * 4 + r] = v;
    else        acc2[nn2 * 4 + r] = v;
  }
}

// fused layer-2 attention: one thread per (node, head)
__global__ __launch_bounds__(256) void attn2(
    const float* __restrict__ qkv2, const int* __restrict__ rowptr,
    const int* __restrict__ csr_src, float* __restrict__ acc2)
{
  int t = blockIdx.x * 256 + threadIdx.x;
  if (t >= NN * 4) return;
  int n = t >> 2, h = t & 3;
  float q = qkv2[n * 12 + h];
  float den = 0.f, acc = 0.f;
  int e1 = rowptr[n + 1];
  for (int j = rowptr[n]; j < e1; ++j) {
    int s = csr_src[j];
    float k = qkv2[s * 12 + 4 + h];
    float v = qkv2[s * 12 + 8 + h];
    float ex = __expf(q * k);
    den += ex; acc += ex * v;
  }
  acc2[t] += acc / fmaxf(den, 1e-16f);
}

__global__ void out_init(float* __restrict__ out, const float* __restrict__ bl)
{
  out[0] = bl[0];
}

__global__ __launch_bounds__(256) void final_reduce(
    const float* __restrict__ acc2, const float* __restrict__ Wl,
    float* __restrict__ out)
{
  __shared__ float red[256];
  float w0 = Wl[0], w1 = Wl[1], w2 = Wl[2], w3 = Wl[3];
  float s = 0.f;
  for (int n = blockIdx.x * 256 + threadIdx.x; n < NN; n += gridDim.x * 256) {
    float4 a = *(const float4*)(acc2 + (size_t)n * 4);
    s += a.x * w0 + a.y * w1 + a.z * w2 + a.w * w3;
  }
  red[threadIdx.x] = s;
  __syncthreads();
  for (int off = 128; off; off >>= 1) {
    if (threadIdx.x < off) red[threadIdx.x] += red[threadIdx.x + off];
    __syncthreads();
  }
  if (threadIdx.x == 0) unsafeAtomicAdd(out, red[0] * (1.0f / NN));
}

extern "C" void kernel_launch(void* const* d_in, const int* in_sizes, int n_in,
                              void* d_out, int out_size, void* d_ws, size_t ws_size,
                              hipStream_t stream)
{
  const float* x   = (const float*)d_in[0];
  const int*   ei  = (const int*)d_in[1];
  const float *Wq1 = (const float*)d_in[2],  *bq1 = (const float*)d_in[3];
  const float *Wk1 = (const float*)d_in[4],  *bk1 = (const float*)d_in[5];
  const float *Wv1 = (const float*)d_in[6],  *bv1 = (const float*)d_in[7];
  const float *Ws1 = (const float*)d_in[8],  *bs1 = (const float*)d_in[9];
  const float *Wq2 = (const float*)d_in[10], *bq2 = (const float*)d_in[11];
  const float *Wk2 = (const float*)d_in[12], *bk2 = (const float*)d_in[13];
  const float *Wv2 = (const float*)d_in[14], *bv2 = (const float*)d_in[15];
  const float *Ws2 = (const float*)d_in[16], *bs2 = (const float*)d_in[17];
  const float *Wl  = (const float*)d_in[18], *bl  = (const float*)d_in[19];
  const int* srcp = ei;
  const int* dstp = ei + NE;

  // workspace layout
  ushort* qkv1 = (ushort*)d_ws;                       // NN*1536 bf16
  ushort* x_bf = qkv1 + (size_t)NN * 1536;            // NN*128 bf16
  ushort* w1bf = x_bf + (size_t)NN * 128;             // 2048*128 bf16
  float*  h1   = (float*)(w1bf + (size_t)2048 * 128); // NN*512 f32
  float*  qkv2 = h1 + (size_t)NN * 512;               // NN*12
  float*  acc2 = qkv2 + (size_t)NN * 12;              // NN*4
  int*   deg     = (int*)(acc2 + (size_t)NN * 4);     // NN
  int*   rowptr  = deg + NN;                          // NN+1
  int*   cursor  = rowptr + NN + 1;                   // NN
  int*   csr_src = cursor + NN;                       // NE

  // CSR build
  hipMemsetAsync(deg, 0, (size_t)NN * sizeof(int), stream);
  count_deg<<<(NE + 255) / 256, 256, 0, stream>>>(dstp, deg, NE);
  scan_k<<<1, 1024, 0, stream>>>(deg, rowptr, cursor);
  scatter_k<<<(NE + 255) / 256, 256, 0, stream>>>(srcp, dstp, cursor, csr_src, NE);

  // fp32 -> bf16 converts (x + stacked W1)
  f2bf_k<<<(NN * 128 / 4 + 255) / 256, 256, 0, stream>>>(x, x_bf, NN * 128 / 4);
  f2bf_k<<<(512 * 128 / 4 + 255) / 256, 256, 0, stream>>>(Wq1, w1bf + 0 * 512 * 128, 512 * 128 / 4);
  f2bf_k<<<(512 * 128 / 4 + 255) / 256, 256, 0, stream>>>(Wk1, w1bf + 1 * 512 * 128, 512 * 128 / 4);
  f2bf_k<<<(512 * 128 / 4 + 255) / 256, 256, 0, stream>>>(Wv1, w1bf + 2 * 512 * 128, 512 * 128 / 4);
  f2bf_k<<<(512 * 128 / 4 + 255) / 256, 256, 0, stream>>>(Ws1, w1bf + 3 * 512 * 128, 512 * 128 / 4);

  // layer-1 projections via MFMA
  {
    dim3 grid((NN + 127) / 128, 32);
    gemm_l1_mfma<<<grid, 256, 0, stream>>>(x_bf, w1bf, bq1, bk1, bv1, bs1,
                                           qkv1, h1);
  }

  attn1<<<(NN + 3) / 4, 256, 0, stream>>>(qkv1, rowptr, csr_src, h1);
  gemm_l2<<<(NN + 63) / 64, 256, 0, stream>>>(
      h1, Wq2, bq2, Wk2, bk2, Wv2, bv2, Ws2, bs2, qkv2, acc2);
  attn2<<<(NN * 4 + 255) / 256, 256, 0, stream>>>(qkv2, rowptr, csr_src, acc2);
  out_init<<<1, 1, 0, stream>>>((float*)d_out, bl);
  final_reduce<<<40, 256, 0, stream>>>(acc2, Wl, (float*)d_out);
}

// Round 5
// 166.580 us; speedup vs baseline: 15.2193x; 1.1215x over previous
//
#include <hip/hip_runtime.h>

#define NN 10000
#define NE 160000

typedef __attribute__((ext_vector_type(8))) short bf16x8;
typedef __attribute__((ext_vector_type(4))) float f32x4;

__device__ inline ushort f2bf(float x) {
  uint u = __float_as_uint(x);
  return (ushort)((u + 0x7fffu + ((u >> 16) & 1u)) >> 16);
}

__device__ inline void unpack8(uint4 u, float* f) {
  f[0] = __uint_as_float(u.x << 16); f[1] = __uint_as_float(u.x & 0xffff0000u);
  f[2] = __uint_as_float(u.y << 16); f[3] = __uint_as_float(u.y & 0xffff0000u);
  f[4] = __uint_as_float(u.z << 16); f[5] = __uint_as_float(u.z & 0xffff0000u);
  f[6] = __uint_as_float(u.w << 16); f[7] = __uint_as_float(u.w & 0xffff0000u);
}

// ---- prep: degree count + fp32->bf16 conversions in one launch -------------
__global__ __launch_bounds__(256) void prep_k(
    const float* __restrict__ x,
    const float* __restrict__ Wq1, const float* __restrict__ Wk1,
    const float* __restrict__ Wv1, const float* __restrict__ Ws1,
    ushort* __restrict__ x_bf, ushort* __restrict__ w1bf,
    const int* __restrict__ dst, int* __restrict__ deg)
{
  int i = blockIdx.x * 256 + threadIdx.x;
  if (i < NE) atomicAdd(&deg[dst[i]], 1);
  const int n4x = NN * 32;          // float4 groups in x
  const int n4w = 512 * 128 / 4;    // 16384 per W
  if (i < n4x) {
    float4 v = ((const float4*)x)[i];
    ushort4 o;
    o.x = f2bf(v.x); o.y = f2bf(v.y); o.z = f2bf(v.z); o.w = f2bf(v.w);
    ((ushort4*)x_bf)[i] = o;
  } else {
    int c = i - n4x;
    if (c < 4 * n4w) {
      int seg = c >> 14, k = c & 16383;
      const float* W = (seg == 0) ? Wq1 : (seg == 1) ? Wk1
                     : (seg == 2) ? Wv1 : Ws1;
      float4 v = ((const float4*)W)[k];
      ushort4 o;
      o.x = f2bf(v.x); o.y = f2bf(v.y); o.z = f2bf(v.z); o.w = f2bf(v.w);
      ((ushort4*)(w1bf + ((size_t)seg << 16)))[k] = o;
    }
  }
}

// ---- layer-1 GEMM: [NN x 128] * [2048 x 128]^T via bf16 MFMA ---------------
__global__ __launch_bounds__(256) void gemm_l1_mfma(
    const ushort* __restrict__ xbf,
    const ushort* __restrict__ wbf,
    const float* __restrict__ bq, const float* __restrict__ bk,
    const float* __restrict__ bv, const float* __restrict__ bs,
    ushort* __restrict__ qkv1,
    float* __restrict__ h1)
{
  __shared__ __align__(16) ushort Al[128 * 128];
  __shared__ __align__(16) ushort Bl[64 * 128];
  const int row0 = blockIdx.x << 7;
  const int ncol0 = blockIdx.y << 6;
  const int tid = threadIdx.x;

  #pragma unroll
  for (int i = 0; i < 8; ++i) {
    int slot = tid + (i << 8);
    int r = slot >> 4, c = slot & 15;
    int gr = row0 + r;
    uint4 v = make_uint4(0u, 0u, 0u, 0u);
    if (gr < NN) v = *(const uint4*)(xbf + (size_t)gr * 128 + (c << 3));
    *(uint4*)(Al + r * 128 + ((c ^ (r & 7)) << 3)) = v;
  }
  #pragma unroll
  for (int i = 0; i < 4; ++i) {
    int slot = tid + (i << 8);
    int r = slot >> 4, c = slot & 15;
    uint4 v = *(const uint4*)(wbf + (size_t)(ncol0 + r) * 128 + (c << 3));
    *(uint4*)(Bl + r * 128 + ((c ^ (r & 7)) << 3)) = v;
  }
  __syncthreads();

  const int wid = tid >> 6, lane = tid & 63;
  const int wm = wid >> 1, wn = wid & 1;
  const int lr = lane & 15, lkg = lane >> 4;

  f32x4 acc[4][2];
  #pragma unroll
  for (int m = 0; m < 4; ++m)
    #pragma unroll
    for (int n = 0; n < 2; ++n) acc[m][n] = (f32x4){0.f, 0.f, 0.f, 0.f};

  #pragma unroll
  for (int ks = 0; ks < 4; ++ks) {
    int c16 = (ks << 2) + lkg;
    bf16x8 a[4], b[2];
    #pragma unroll
    for (int mf = 0; mf < 4; ++mf) {
      int r = (wm << 6) + (mf << 4) + lr;
      a[mf] = *(const bf16x8*)(Al + r * 128 + ((c16 ^ (r & 7)) << 3));
    }
    #pragma unroll
    for (int nf = 0; nf < 2; ++nf) {
      int r = (wn << 5) + (nf << 4) + lr;
      b[nf] = *(const bf16x8*)(Bl + r * 128 + ((c16 ^ (r & 7)) << 3));
    }
    #pragma unroll
    for (int mf = 0; mf < 4; ++mf)
      #pragma unroll
      for (int nf = 0; nf < 2; ++nf)
        acc[mf][nf] = __builtin_amdgcn_mfma_f32_16x16x32_bf16(
            a[mf], b[nf], acc[mf][nf], 0, 0, 0);
  }

  const int seg = ncol0 >> 9;
  const int colInSeg = ncol0 & 511;
  const float* bias = (seg == 0) ? bq : (seg == 1) ? bk : (seg == 2) ? bv : bs;
  #pragma unroll
  for (int mf = 0; mf < 4; ++mf) {
    #pragma unroll
    for (int nf = 0; nf < 2; ++nf) {
      int col = colInSeg + (wn << 5) + (nf << 4) + lr;
      float bb = bias[col];
      #pragma unroll
      for (int r = 0; r < 4; ++r) {
        int row = row0 + (wm << 6) + (mf << 4) + (lkg << 2) + r;
        if (row >= NN) continue;
        float val = acc[mf][nf][r] + bb;
        if (seg < 3) qkv1[(size_t)row * 1536 + (seg << 9) + col] = f2bf(val);
        else         h1[(size_t)row * 512 + col] = val;
      }
    }
  }
}

// ---- CSR build ------------------------------------------------------------
__global__ __launch_bounds__(1024) void scan_k(
    const int* __restrict__ deg, int* __restrict__ rowptr,
    int* __restrict__ cursor)
{
  __shared__ int part[1024];
  int tid = threadIdx.x;
  int base = tid * 10;
  int loc[10]; int s = 0;
  #pragma unroll
  for (int i = 0; i < 10; ++i) {
    int v = (base + i < NN) ? deg[base + i] : 0;
    loc[i] = s; s += v;
  }
  part[tid] = s;
  __syncthreads();
  for (int off = 1; off < 1024; off <<= 1) {
    int v = (tid >= off) ? part[tid - off] : 0;
    __syncthreads();
    part[tid] += v;
    __syncthreads();
  }
  int prev = (tid == 0) ? 0 : part[tid - 1];
  #pragma unroll
  for (int i = 0; i < 10; ++i) {
    int idx = base + i;
    if (idx < NN) { int r = prev + loc[i]; rowptr[idx] = r; cursor[idx] = r; }
  }
  if (tid == 1023) rowptr[NN] = part[1023];
}

__global__ __launch_bounds__(256) void scatter_k(
    const int* __restrict__ src, const int* __restrict__ dst,
    int* __restrict__ cursor, int* __restrict__ csr_src, int E)
{
  int e = blockIdx.x * 256 + threadIdx.x;
  if (e >= E) return;
  int pos = atomicAdd(&cursor[dst[e]], 1);
  csr_src[pos] = src[e];
}

// ---- fused layer-1 attention: one wave per node, 4-edge unrolled -----------
#define EDGE_BODY(kk, vv)                                                  \
  {                                                                        \
    float kf[8], vf[8];                                                    \
    unpack8(kk, kf); unpack8(vv, vf);                                      \
    float t = q[0]*kf[0] + q[1]*kf[1] + q[2]*kf[2] + q[3]*kf[3]            \
            + q[4]*kf[4] + q[5]*kf[5] + q[6]*kf[6] + q[7]*kf[7];           \
    t += __shfl_xor(t, 1);                                                 \
    t += __shfl_xor(t, 2);                                                 \
    t += __shfl_xor(t, 4);                                                 \
    t += __shfl_xor(t, 8);                                                 \
    float ex = __expf(t);                                                  \
    den += ex;                                                             \
    _Pragma("unroll")                                                      \
    for (int i = 0; i < 8; ++i) acc[i] += ex * vf[i];                      \
  }

__global__ __launch_bounds__(256) void attn1(
    const ushort* __restrict__ qkv, const int* __restrict__ rowptr,
    const int* __restrict__ csr_src, float* __restrict__ h1)
{
  int n = blockIdx.x * 4 + (threadIdx.x >> 6);
  if (n >= NN) return;
  int lane = threadIdx.x & 63;
  int h = lane >> 4, c0 = (lane & 15) << 3;
  const int off = h * 128 + c0;
  float q[8];
  unpack8(*(const uint4*)(qkv + (size_t)n * 1536 + off), q);
  #pragma unroll
  for (int i = 0; i < 8; ++i) q[i] *= 0.08838834764831845f;  // 1/sqrt(128)
  float acc[8] = {};
  float den = 0.f;
  int j = rowptr[n], e1 = rowptr[n + 1];
  for (; j + 3 < e1; j += 4) {
    int s0 = csr_src[j], s1 = csr_src[j + 1];
    int s2 = csr_src[j + 2], s3 = csr_src[j + 3];
    const ushort* b0 = qkv + (size_t)s0 * 1536 + off;
    const ushort* b1 = qkv + (size_t)s1 * 1536 + off;
    const ushort* b2 = qkv + (size_t)s2 * 1536 + off;
    const ushort* b3 = qkv + (size_t)s3 * 1536 + off;
    uint4 k0 = *(const uint4*)(b0 + 512), v0 = *(const uint4*)(b0 + 1024);
    uint4 k1 = *(const uint4*)(b1 + 512), v1 = *(const uint4*)(b1 + 1024);
    uint4 k2 = *(const uint4*)(b2 + 512), v2 = *(const uint4*)(b2 + 1024);
    uint4 k3 = *(const uint4*)(b3 + 512), v3 = *(const uint4*)(b3 + 1024);
    EDGE_BODY(k0, v0)
    EDGE_BODY(k1, v1)
    EDGE_BODY(k2, v2)
    EDGE_BODY(k3, v3)
  }
  for (; j < e1; ++j) {
    int s = csr_src[j];
    const ushort* b = qkv + (size_t)s * 1536 + off;
    uint4 kk = *(const uint4*)(b + 512), vv = *(const uint4*)(b + 1024);
    EDGE_BODY(kk, vv)
  }
  float inv = 1.f / fmaxf(den, 1e-16f);
  float* op = h1 + (size_t)n * 512 + off;
  float4 s0 = *(const float4*)op, s1 = *(const float4*)(op + 4);
  float4 o0, o1;
  o0.x = fmaxf(s0.x + acc[0] * inv, 0.f);
  o0.y = fmaxf(s0.y + acc[1] * inv, 0.f);
  o0.z = fmaxf(s0.z + acc[2] * inv, 0.f);
  o0.w = fmaxf(s0.w + acc[3] * inv, 0.f);
  o1.x = fmaxf(s1.x + acc[4] * inv, 0.f);
  o1.y = fmaxf(s1.y + acc[5] * inv, 0.f);
  o1.z = fmaxf(s1.z + acc[6] * inv, 0.f);
  o1.w = fmaxf(s1.w + acc[7] * inv, 0.f);
  *(float4*)op = o0;
  *(float4*)(op + 4) = o1;
}

// ---- layer-2 projections ---------------------------------------------------
__global__ __launch_bounds__(256) void gemm_l2(
    const float* __restrict__ h1,
    const float* __restrict__ Wq, const float* __restrict__ bq,
    const float* __restrict__ Wk, const float* __restrict__ bk,
    const float* __restrict__ Wv, const float* __restrict__ bv,
    const float* __restrict__ Ws, const float* __restrict__ bs,
    float* __restrict__ qkv2, float* __restrict__ acc2)
{
  __shared__ float red[4][64][17];
  int n0 = blockIdx.x * 64;
  int wid = threadIdx.x >> 6, lane = threadIdx.x & 63;
  int n = n0 + lane;
  const float* Wm[4] = {Wq, Wk, Wv, Ws};
  float s[16] = {};
  if (n < NN) {
    const float* a = h1 + (size_t)n * 512 + wid * 128;
    #pragma unroll 4
    for (int i = 0; i < 128; i += 4) {
      float4 av = *(const float4*)(a + i);
      #pragma unroll
      for (int j = 0; j < 16; ++j) {
        const float* w = Wm[j >> 2] + (size_t)(j & 3) * 512 + wid * 128 + i;
        s[j] += av.x * w[0] + av.y * w[1] + av.z * w[2] + av.w * w[3];
      }
    }
  }
  #pragma unroll
  for (int j = 0; j < 16; ++j) red[wid][lane][j] = s[j];
  __syncthreads();
  #pragma unroll
  for (int q = 0; q < 4; ++q) {
    int idx = threadIdx.x * 4 + q;
    int ln = idx >> 4, j = idx & 15;
    int nn2 = n0 + ln;
    if (nn2 >= NN) continue;
    float v = red[0][ln][j] + red[1][ln][j] + red[2][ln][j] + red[3][ln][j];
    int sg = j >> 2, r = j & 3;
    const float* bb = (sg == 0) ? bq : (sg == 1) ? bk : (sg == 2) ? bv : bs;
    v += bb[r];
    if (sg < 3) qkv2[nn2 * 12 + sg * 4 + r] = v;
    else        acc2[nn2 * 4 + r] = v;
  }
}

// ---- layer-2 attention: 4 threads per (node, head), shuffle combine --------
__global__ __launch_bounds__(256) void attn2(
    const float* __restrict__ qkv2, const int* __restrict__ rowptr,
    const int* __restrict__ csr_src, float* __restrict__ acc2)
{
  int t = blockIdx.x * 256 + threadIdx.x;
  if (t >= NN * 16) return;
  int n = t >> 4, h = (t >> 2) & 3, part = t & 3;
  float q = qkv2[n * 12 + h];
  float den = 0.f, acc = 0.f;
  int e1 = rowptr[n + 1];
  for (int j = rowptr[n] + part; j < e1; j += 4) {
    int s = csr_src[j];
    float k = qkv2[s * 12 + 4 + h];
    float v = qkv2[s * 12 + 8 + h];
    float ex = __expf(q * k);
    den += ex; acc += ex * v;
  }
  den += __shfl_xor(den, 1); acc += __shfl_xor(acc, 1);
  den += __shfl_xor(den, 2); acc += __shfl_xor(acc, 2);
  if (part == 0) acc2[n * 4 + h] += acc / fmaxf(den, 1e-16f);
}

// ---- final: out = bl + mean(acc2 . Wl), single block -----------------------
__global__ __launch_bounds__(1024) void final_k(
    const float* __restrict__ acc2, const float* __restrict__ Wl,
    const float* __restrict__ bl, float* __restrict__ out)
{
  __shared__ float red[1024];
  float w0 = Wl[0], w1 = Wl[1], w2 = Wl[2], w3 = Wl[3];
  float s = 0.f;
  for (int n = threadIdx.x; n < NN; n += 1024) {
    float4 a = ((const float4*)acc2)[n];
    s += a.x * w0 + a.y * w1 + a.z * w2 + a.w * w3;
  }
  red[threadIdx.x] = s;
  __syncthreads();
  for (int off = 512; off; off >>= 1) {
    if (threadIdx.x < off) red[threadIdx.x] += red[threadIdx.x + off];
    __syncthreads();
  }
  if (threadIdx.x == 0) out[0] = bl[0] + red[0] * (1.0f / NN);
}

extern "C" void kernel_launch(void* const* d_in, const int* in_sizes, int n_in,
                              void* d_out, int out_size, void* d_ws, size_t ws_size,
                              hipStream_t stream)
{
  const float* x   = (const float*)d_in[0];
  const int*   ei  = (const int*)d_in[1];
  const float *Wq1 = (const float*)d_in[2],  *bq1 = (const float*)d_in[3];
  const float *Wk1 = (const float*)d_in[4],  *bk1 = (const float*)d_in[5];
  const float *Wv1 = (const float*)d_in[6],  *bv1 = (const float*)d_in[7];
  const float *Ws1 = (const float*)d_in[8],  *bs1 = (const float*)d_in[9];
  const float *Wq2 = (const float*)d_in[10], *bq2 = (const float*)d_in[11];
  const float *Wk2 = (const float*)d_in[12], *bk2 = (const float*)d_in[13];
  const float *Wv2 = (const float*)d_in[14], *bv2 = (const float*)d_in[15];
  const float *Ws2 = (const float*)d_in[16], *bs2 = (const float*)d_in[17];
  const float *Wl  = (const float*)d_in[18], *bl  = (const float*)d_in[19];
  const int* srcp = ei;
  const int* dstp = ei + NE;

  ushort* qkv1 = (ushort*)d_ws;                       // NN*1536 bf16
  ushort* x_bf = qkv1 + (size_t)NN * 1536;            // NN*128 bf16
  ushort* w1bf = x_bf + (size_t)NN * 128;             // 2048*128 bf16
  float*  h1   = (float*)(w1bf + (size_t)2048 * 128); // NN*512 f32
  float*  qkv2 = h1 + (size_t)NN * 512;               // NN*12
  float*  acc2 = qkv2 + (size_t)NN * 12;              // NN*4
  int*   deg     = (int*)(acc2 + (size_t)NN * 4);     // NN
  int*   rowptr  = deg + NN;                          // NN+1
  int*   cursor  = rowptr + NN + 1;                   // NN
  int*   csr_src = cursor + NN;                       // NE

  hipMemsetAsync(deg, 0, (size_t)NN * sizeof(int), stream);
  {
    const int total = NN * 32 + 4 * (512 * 128 / 4);  // 385536
    prep_k<<<(total + 255) / 256, 256, 0, stream>>>(
        x, Wq1, Wk1, Wv1, Ws1, x_bf, w1bf, dstp, deg);
  }
  scan_k<<<1, 1024, 0, stream>>>(deg, rowptr, cursor);
  scatter_k<<<(NE + 255) / 256, 256, 0, stream>>>(srcp, dstp, cursor, csr_src, NE);

  {
    dim3 grid((NN + 127) / 128, 32);
    gemm_l1_mfma<<<grid, 256, 0, stream>>>(x_bf, w1bf, bq1, bk1, bv1, bs1,
                                           qkv1, h1);
  }

  attn1<<<(NN + 3) / 4, 256, 0, stream>>>(qkv1, rowptr, csr_src, h1);
  gemm_l2<<<(NN + 63) / 64, 256, 0, stream>>>(
      h1, Wq2, bq2, Wk2, bk2, Wv2, bv2, Ws2, bs2, qkv2, acc2);
  attn2<<<(NN * 16 + 255) / 256, 256, 0, stream>>>(qkv2, rowptr, csr_src, acc2);
  final_k<<<1, 1024, 0, stream>>>(acc2, Wl, bl, (float*)d_out);
}

// Round 6
// 135.544 us; speedup vs baseline: 18.7042x; 1.2290x over previous
//
#include <hip/hip_runtime.h>
#include <math.h>

#define NN 10000
#define NE 160000
#define NROWT 79              // ceil(NN/128)
#define NGEMM (NROWT * 32)

typedef __attribute__((ext_vector_type(8))) short bf16x8;
typedef __attribute__((ext_vector_type(4))) float f32x4;
typedef __attribute__((ext_vector_type(2))) float f32x2;

#if defined(__has_builtin)
#if __has_builtin(__builtin_amdgcn_cvt_pk_fp8_f32) && __has_builtin(__builtin_amdgcn_cvt_pk_f32_fp8)
#define HW_FP8 1
#endif
#endif

__device__ inline ushort f2bf(float x) {
  uint u = __float_as_uint(x);
  return (ushort)((u + 0x7fffu + ((u >> 16) & 1u)) >> 16);
}

__device__ inline void unpack8(uint4 u, float* f) {
  f[0] = __uint_as_float(u.x << 16); f[1] = __uint_as_float(u.x & 0xffff0000u);
  f[2] = __uint_as_float(u.y << 16); f[3] = __uint_as_float(u.y & 0xffff0000u);
  f[4] = __uint_as_float(u.z << 16); f[5] = __uint_as_float(u.z & 0xffff0000u);
  f[6] = __uint_as_float(u.w << 16); f[7] = __uint_as_float(u.w & 0xffff0000u);
}

#ifndef HW_FP8
__device__ inline float fp8_dec1(uint b) {
  uint s = b >> 7, e = (b >> 3) & 15, m = b & 7;
  float v = (e == 0) ? ldexpf((float)m, -9) : ldexpf((float)(8 + m), (int)e - 10);
  return s ? -v : v;
}
__device__ inline uint fp8_enc1(float x) {
  uint s = (__float_as_uint(x) >> 31) << 7;
  float a = fabsf(x);
  if (!(a < 448.f)) return s | 0x7e;
  if (a < 9.765625e-4f) return s;
  int e; float m = frexpf(a, &e);
  int E = e - 1, q;
  if (E < -6) {
    q = (int)rintf(ldexpf(a, 9));
    if (q == 0) return s;
    if (q >= 8) return s | 8;
    return s | (uint)q;
  }
  q = (int)rintf(ldexpf(m, 4));
  if (q == 16) { q = 8; ++E; }
  if (E > 8 || (E == 8 && q == 15)) return s | 0x7e;
  return s | ((uint)(E + 7) << 3) | (uint)(q - 8);
}
#endif

__device__ inline uint pack4_fp8(float a, float b, float c, float d) {
#ifdef HW_FP8
  uint w = (uint)__builtin_amdgcn_cvt_pk_fp8_f32(a, b, 0, false);
  w = (uint)__builtin_amdgcn_cvt_pk_fp8_f32(c, d, (int)w, true);
  return w;
#else
  return fp8_enc1(a) | (fp8_enc1(b) << 8) | (fp8_enc1(c) << 16) | (fp8_enc1(d) << 24);
#endif
}

__device__ inline void dec8_fp8(uint2 u, float* f) {
#ifdef HW_FP8
  f32x2 p0 = __builtin_amdgcn_cvt_pk_f32_fp8((int)u.x, false);
  f32x2 p1 = __builtin_amdgcn_cvt_pk_f32_fp8((int)u.x, true);
  f32x2 p2 = __builtin_amdgcn_cvt_pk_f32_fp8((int)u.y, false);
  f32x2 p3 = __builtin_amdgcn_cvt_pk_f32_fp8((int)u.y, true);
  f[0] = p0.x; f[1] = p0.y; f[2] = p1.x; f[3] = p1.y;
  f[4] = p2.x; f[5] = p2.y; f[6] = p3.x; f[7] = p3.y;
#else
  f[0] = fp8_dec1(u.x & 255); f[1] = fp8_dec1((u.x >> 8) & 255);
  f[2] = fp8_dec1((u.x >> 16) & 255); f[3] = fp8_dec1(u.x >> 24);
  f[4] = fp8_dec1(u.y & 255); f[5] = fp8_dec1((u.y >> 8) & 255);
  f[6] = fp8_dec1((u.y >> 16) & 255); f[7] = fp8_dec1(u.y >> 24);
#endif
}

// ---- prep: degree count + fp32->bf16 conversions in one launch -------------
__global__ __launch_bounds__(256) void prep_k(
    const float* __restrict__ x,
    const float* __restrict__ Wq1, const float* __restrict__ Wk1,
    const float* __restrict__ Wv1, const float* __restrict__ Ws1,
    ushort* __restrict__ x_bf, ushort* __restrict__ w1bf,
    const int* __restrict__ dst, int* __restrict__ deg)
{
  int i = blockIdx.x * 256 + threadIdx.x;
  if (i < NE) atomicAdd(&deg[dst[i]], 1);
  const int n4x = NN * 32;
  const int n4w = 512 * 128 / 4;
  if (i < n4x) {
    float4 v = ((const float4*)x)[i];
    ushort4 o;
    o.x = f2bf(v.x); o.y = f2bf(v.y); o.z = f2bf(v.z); o.w = f2bf(v.w);
    ((ushort4*)x_bf)[i] = o;
  } else {
    int c = i - n4x;
    if (c < 4 * n4w) {
      int seg = c >> 14, k = c & 16383;
      const float* W = (seg == 0) ? Wq1 : (seg == 1) ? Wk1
                     : (seg == 2) ? Wv1 : Ws1;
      float4 v = ((const float4*)W)[k];
      ushort4 o;
      o.x = f2bf(v.x); o.y = f2bf(v.y); o.z = f2bf(v.z); o.w = f2bf(v.w);
      ((ushort4*)(w1bf + ((size_t)seg << 16)))[k] = o;
    }
  }
}

// ---- CSR scan --------------------------------------------------------------
__global__ __launch_bounds__(1024) void scan_k(
    const int* __restrict__ deg, int* __restrict__ rowptr,
    int* __restrict__ cursor)
{
  __shared__ int part[1024];
  int tid = threadIdx.x;
  int base = tid * 10;
  int loc[10]; int s = 0;
  #pragma unroll
  for (int i = 0; i < 10; ++i) {
    int v = (base + i < NN) ? deg[base + i] : 0;
    loc[i] = s; s += v;
  }
  part[tid] = s;
  __syncthreads();
  for (int off = 1; off < 1024; off <<= 1) {
    int v = (tid >= off) ? part[tid - off] : 0;
    __syncthreads();
    part[tid] += v;
    __syncthreads();
  }
  int prev = (tid == 0) ? 0 : part[tid - 1];
  #pragma unroll
  for (int i = 0; i < 10; ++i) {
    int idx = base + i;
    if (idx < NN) { int r = prev + loc[i]; rowptr[idx] = r; cursor[idx] = r; }
  }
  if (tid == 1023) rowptr[NN] = part[1023];
}

// ---- fused: layer-1 GEMM (bf16 MFMA) + CSR scatter -------------------------
// gemm blocks: tile 128(M) x 64(N), K=128 one LDS shot. seg = q|k|v|skip.
// q -> bf16 [NN][512]; k,v -> fp8 [NN][512] (swapped-MFMA epilogue packs 4
// consecutive channels per lane); skip -> f32 h1.
__global__ __launch_bounds__(256) void gemm_scatter(
    const ushort* __restrict__ xbf, const ushort* __restrict__ wbf,
    const float* __restrict__ bq, const float* __restrict__ bk,
    const float* __restrict__ bv, const float* __restrict__ bs,
    ushort* __restrict__ qbf, unsigned char* __restrict__ k8,
    unsigned char* __restrict__ v8, float* __restrict__ h1,
    const int* __restrict__ src, const int* __restrict__ dst,
    int* __restrict__ cursor, int* __restrict__ csr_src)
{
  if (blockIdx.x >= NGEMM) {   // ---- scatter part ----
    int e = (blockIdx.x - NGEMM) * 256 + threadIdx.x;
    if (e < NE) {
      int pos = atomicAdd(&cursor[dst[e]], 1);
      csr_src[pos] = src[e];
    }
    return;
  }
  __shared__ __align__(16) ushort Al[128 * 128];
  __shared__ __align__(16) ushort Bl[64 * 128];
  const int row0 = (blockIdx.x % NROWT) << 7;
  const int ncol0 = (blockIdx.x / NROWT) << 6;
  const int tid = threadIdx.x;

  #pragma unroll
  for (int i = 0; i < 8; ++i) {
    int slot = tid + (i << 8);
    int r = slot >> 4, c = slot & 15;
    int gr = row0 + r;
    uint4 v = make_uint4(0u, 0u, 0u, 0u);
    if (gr < NN) v = *(const uint4*)(xbf + (size_t)gr * 128 + (c << 3));
    *(uint4*)(Al + r * 128 + ((c ^ (r & 7)) << 3)) = v;
  }
  #pragma unroll
  for (int i = 0; i < 4; ++i) {
    int slot = tid + (i << 8);
    int r = slot >> 4, c = slot & 15;
    uint4 v = *(const uint4*)(wbf + (size_t)(ncol0 + r) * 128 + (c << 3));
    *(uint4*)(Bl + r * 128 + ((c ^ (r & 7)) << 3)) = v;
  }
  __syncthreads();

  const int wid = tid >> 6, lane = tid & 63;
  const int wm = wid >> 1, wn = wid & 1;
  const int lr = lane & 15, lkg = lane >> 4;
  const int seg = ncol0 >> 9;
  const int colInSeg = ncol0 & 511;
  const bool swp = (seg == 1) || (seg == 2);   // k or v -> fp8, D^T layout

  f32x4 acc[4][2];
  #pragma unroll
  for (int m = 0; m < 4; ++m)
    #pragma unroll
    for (int n = 0; n < 2; ++n) acc[m][n] = (f32x4){0.f, 0.f, 0.f, 0.f};

  #pragma unroll
  for (int ks = 0; ks < 4; ++ks) {
    int c16 = (ks << 2) + lkg;
    bf16x8 a[4], b[2];
    #pragma unroll
    for (int mf = 0; mf < 4; ++mf) {
      int r = (wm << 6) + (mf << 4) + lr;
      a[mf] = *(const bf16x8*)(Al + r * 128 + ((c16 ^ (r & 7)) << 3));
    }
    #pragma unroll
    for (int nf = 0; nf < 2; ++nf) {
      int r = (wn << 5) + (nf << 4) + lr;
      b[nf] = *(const bf16x8*)(Bl + r * 128 + ((c16 ^ (r & 7)) << 3));
    }
    if (swp) {
      #pragma unroll
      for (int mf = 0; mf < 4; ++mf)
        #pragma unroll
        for (int nf = 0; nf < 2; ++nf)
          acc[mf][nf] = __builtin_amdgcn_mfma_f32_16x16x32_bf16(
              b[nf], a[mf], acc[mf][nf], 0, 0, 0);
    } else {
      #pragma unroll
      for (int mf = 0; mf < 4; ++mf)
        #pragma unroll
        for (int nf = 0; nf < 2; ++nf)
          acc[mf][nf] = __builtin_amdgcn_mfma_f32_16x16x32_bf16(
              a[mf], b[nf], acc[mf][nf], 0, 0, 0);
    }
  }

  const float* bias = (seg == 0) ? bq : (seg == 1) ? bk : (seg == 2) ? bv : bs;
  if (swp) {
    // D^T: lane holds 4 consecutive channels (ch0 = ... + lkg*4) of x-row
    unsigned char* out8 = (seg == 1) ? k8 : v8;
    #pragma unroll
    for (int mf = 0; mf < 4; ++mf) {
      int xrow = row0 + (wm << 6) + (mf << 4) + lr;
      if (xrow >= NN) continue;
      #pragma unroll
      for (int nf = 0; nf < 2; ++nf) {
        int ch = colInSeg + (wn << 5) + (nf << 4) + (lkg << 2);
        float4 bb = *(const float4*)(bias + ch);
        uint w = pack4_fp8(acc[mf][nf][0] + bb.x, acc[mf][nf][1] + bb.y,
                           acc[mf][nf][2] + bb.z, acc[mf][nf][3] + bb.w);
        *(uint*)(out8 + (size_t)xrow * 512 + ch) = w;
      }
    }
  } else {
    #pragma unroll
    for (int mf = 0; mf < 4; ++mf) {
      #pragma unroll
      for (int nf = 0; nf < 2; ++nf) {
        int col = colInSeg + (wn << 5) + (nf << 4) + lr;
        float bb = bias[col];
        #pragma unroll
        for (int r = 0; r < 4; ++r) {
          int row = row0 + (wm << 6) + (mf << 4) + (lkg << 2) + r;
          if (row >= NN) continue;
          float val = acc[mf][nf][r] + bb;
          if (seg == 0) qbf[(size_t)row * 512 + col] = f2bf(val);
          else          h1[(size_t)row * 512 + col] = val;
        }
      }
    }
  }
}

// ---- fused layer-1 attention: 2 waves per node, fp8 k/v gather -------------
#define EDGE8(ku, vu)                                                      \
  {                                                                        \
    float kf[8], vf[8];                                                    \
    dec8_fp8(ku, kf); dec8_fp8(vu, vf);                                    \
    float t = q[0]*kf[0] + q[1]*kf[1] + q[2]*kf[2] + q[3]*kf[3]            \
            + q[4]*kf[4] + q[5]*kf[5] + q[6]*kf[6] + q[7]*kf[7];           \
    t += __shfl_xor(t, 1);                                                 \
    t += __shfl_xor(t, 2);                                                 \
    t += __shfl_xor(t, 4);                                                 \
    t += __shfl_xor(t, 8);                                                 \
    float ex = __expf(t);                                                  \
    den += ex;                                                             \
    _Pragma("unroll")                                                      \
    for (int i = 0; i < 8; ++i) acc[i] += ex * vf[i];                      \
  }

__global__ __launch_bounds__(256) void attn1(
    const ushort* __restrict__ qbf, const unsigned char* __restrict__ k8,
    const unsigned char* __restrict__ v8, const int* __restrict__ rowptr,
    const int* __restrict__ csr_src, float* __restrict__ h1)
{
  __shared__ float part[2][64][9];
  int slot = threadIdx.x >> 7;          // node within block (2)
  int sub = (threadIdx.x >> 6) & 1;     // wave within node (2)
  int n = blockIdx.x * 2 + slot;        // NN even -> always valid
  int lane = threadIdx.x & 63;
  int h = lane >> 4, c0 = (lane & 15) << 3;
  const int off = h * 128 + c0;
  float q[8];
  unpack8(*(const uint4*)(qbf + (size_t)n * 512 + off), q);
  #pragma unroll
  for (int i = 0; i < 8; ++i) q[i] *= 0.08838834764831845f;  // 1/sqrt(128)
  float acc[8] = {};
  float den = 0.f;
  int j = rowptr[n] + sub * 2, e1 = rowptr[n + 1];
  for (; j + 1 < e1; j += 4) {          // pairs: sub0 {0,1,4,5..}, sub1 {2,3,..}
    int s0 = csr_src[j], s1 = csr_src[j + 1];
    uint2 ka = *(const uint2*)(k8 + (size_t)s0 * 512 + off);
    uint2 va = *(const uint2*)(v8 + (size_t)s0 * 512 + off);
    uint2 kb = *(const uint2*)(k8 + (size_t)s1 * 512 + off);
    uint2 vb = *(const uint2*)(v8 + (size_t)s1 * 512 + off);
    EDGE8(ka, va)
    EDGE8(kb, vb)
  }
  if (j < e1) {
    int s0 = csr_src[j];
    uint2 ka = *(const uint2*)(k8 + (size_t)s0 * 512 + off);
    uint2 va = *(const uint2*)(v8 + (size_t)s0 * 512 + off);
    EDGE8(ka, va)
  }
  if (sub == 1) {
    #pragma unroll
    for (int i = 0; i < 8; ++i) part[slot][lane][i] = acc[i];
    part[slot][lane][8] = den;
  }
  __syncthreads();
  if (sub == 0) {
    #pragma unroll
    for (int i = 0; i < 8; ++i) acc[i] += part[slot][lane][i];
    den += part[slot][lane][8];
    float inv = 1.f / fmaxf(den, 1e-16f);
    float* op = h1 + (size_t)n * 512 + off;
    float4 s0 = *(const float4*)op, s1 = *(const float4*)(op + 4);
    float4 o0, o1;
    o0.x = fmaxf(s0.x + acc[0] * inv, 0.f);
    o0.y = fmaxf(s0.y + acc[1] * inv, 0.f);
    o0.z = fmaxf(s0.z + acc[2] * inv, 0.f);
    o0.w = fmaxf(s0.w + acc[3] * inv, 0.f);
    o1.x = fmaxf(s1.x + acc[4] * inv, 0.f);
    o1.y = fmaxf(s1.y + acc[5] * inv, 0.f);
    o1.z = fmaxf(s1.z + acc[6] * inv, 0.f);
    o1.w = fmaxf(s1.w + acc[7] * inv, 0.f);
    *(float4*)op = o0;
    *(float4*)(op + 4) = o1;
  }
}

// ---- layer-2 projections ---------------------------------------------------
__global__ __launch_bounds__(256) void gemm_l2(
    const float* __restrict__ h1,
    const float* __restrict__ Wq, const float* __restrict__ bq,
    const float* __restrict__ Wk, const float* __restrict__ bk,
    const float* __restrict__ Wv, const float* __restrict__ bv,
    const float* __restrict__ Ws, const float* __restrict__ bs,
    float* __restrict__ qkv2, float* __restrict__ acc2)
{
  __shared__ float red[4][64][17];
  int n0 = blockIdx.x * 64;
  int wid = threadIdx.x >> 6, lane = threadIdx.x & 63;
  int n = n0 + lane;
  const float* Wm[4] = {Wq, Wk, Wv, Ws};
  float s[16] = {};
  if (n < NN) {
    const float* a = h1 + (size_t)n * 512 + wid * 128;
    #pragma unroll 4
    for (int i = 0; i < 128; i += 4) {
      float4 av = *(const float4*)(a + i);
      #pragma unroll
      for (int j = 0; j < 16; ++j) {
        const float* w = Wm[j >> 2] + (size_t)(j & 3) * 512 + wid * 128 + i;
        s[j] += av.x * w[0] + av.y * w[1] + av.z * w[2] + av.w * w[3];
      }
    }
  }
  #pragma unroll
  for (int j = 0; j < 16; ++j) red[wid][lane][j] = s[j];
  __syncthreads();
  #pragma unroll
  for (int q = 0; q < 4; ++q) {
    int idx = threadIdx.x * 4 + q;
    int ln = idx >> 4, j = idx & 15;
    int nn2 = n0 + ln;
    if (nn2 >= NN) continue;
    float v = red[0][ln][j] + red[1][ln][j] + red[2][ln][j] + red[3][ln][j];
    int sg = j >> 2, r = j & 3;
    const float* bb = (sg == 0) ? bq : (sg == 1) ? bk : (sg == 2) ? bv : bs;
    v += bb[r];
    if (sg < 3) qkv2[nn2 * 12 + sg * 4 + r] = v;
    else        acc2[nn2 * 4 + r] = v;
  }
}

// ---- layer-2 attention: 4 threads per (node, head) -------------------------
__global__ __launch_bounds__(256) void attn2(
    const float* __restrict__ qkv2, const int* __restrict__ rowptr,
    const int* __restrict__ csr_src, float* __restrict__ acc2)
{
  int t = blockIdx.x * 256 + threadIdx.x;
  if (t >= NN * 16) return;
  int n = t >> 4, h = (t >> 2) & 3, part = t & 3;
  float q = qkv2[n * 12 + h];
  float den = 0.f, acc = 0.f;
  int e1 = rowptr[n + 1];
  for (int j = rowptr[n] + part; j < e1; j += 4) {
    int s = csr_src[j];
    float k = qkv2[s * 12 + 4 + h];
    float v = qkv2[s * 12 + 8 + h];
    float ex = __expf(q * k);
    den += ex; acc += ex * v;
  }
  den += __shfl_xor(den, 1); acc += __shfl_xor(acc, 1);
  den += __shfl_xor(den, 2); acc += __shfl_xor(acc, 2);
  if (part == 0) acc2[n * 4 + h] += acc / fmaxf(den, 1e-16f);
}

// ---- final: out = bl + mean(acc2 . Wl) -------------------------------------
__global__ __launch_bounds__(1024) void final_k(
    const float* __restrict__ acc2, const float* __restrict__ Wl,
    const float* __restrict__ bl, float* __restrict__ out)
{
  __shared__ float red[1024];
  float w0 = Wl[0], w1 = Wl[1], w2 = Wl[2], w3 = Wl[3];
  float s = 0.f;
  for (int n = threadIdx.x; n < NN; n += 1024) {
    float4 a = ((const float4*)acc2)[n];
    s += a.x * w0 + a.y * w1 + a.z * w2 + a.w * w3;
  }
  red[threadIdx.x] = s;
  __syncthreads();
  for (int off = 512; off; off >>= 1) {
    if (threadIdx.x < off) red[threadIdx.x] += red[threadIdx.x + off];
    __syncthreads();
  }
  if (threadIdx.x == 0) out[0] = bl[0] + red[0] * (1.0f / NN);
}

extern "C" void kernel_launch(void* const* d_in, const int* in_sizes, int n_in,
                              void* d_out, int out_size, void* d_ws, size_t ws_size,
                              hipStream_t stream)
{
  const float* x   = (const float*)d_in[0];
  const int*   ei  = (const int*)d_in[1];
  const float *Wq1 = (const float*)d_in[2],  *bq1 = (const float*)d_in[3];
  const float *Wk1 = (const float*)d_in[4],  *bk1 = (const float*)d_in[5];
  const float *Wv1 = (const float*)d_in[6],  *bv1 = (const float*)d_in[7];
  const float *Ws1 = (const float*)d_in[8],  *bs1 = (const float*)d_in[9];
  const float *Wq2 = (const float*)d_in[10], *bq2 = (const float*)d_in[11];
  const float *Wk2 = (const float*)d_in[12], *bk2 = (const float*)d_in[13];
  const float *Wv2 = (const float*)d_in[14], *bv2 = (const float*)d_in[15];
  const float *Ws2 = (const float*)d_in[16], *bs2 = (const float*)d_in[17];
  const float *Wl  = (const float*)d_in[18], *bl  = (const float*)d_in[19];
  const int* srcp = ei;
  const int* dstp = ei + NE;

  ushort* qbf  = (ushort*)d_ws;                        // NN*512 bf16
  ushort* x_bf = qbf + (size_t)NN * 512;               // NN*128 bf16
  ushort* w1bf = x_bf + (size_t)NN * 128;              // 2048*128 bf16
  unsigned char* k8 = (unsigned char*)(w1bf + (size_t)2048 * 128); // NN*512 B
  unsigned char* v8 = k8 + (size_t)NN * 512;           // NN*512 B
  float*  h1   = (float*)(v8 + (size_t)NN * 512);      // NN*512 f32
  float*  qkv2 = h1 + (size_t)NN * 512;                // NN*12
  float*  acc2 = qkv2 + (size_t)NN * 12;               // NN*4
  int*   deg     = (int*)(acc2 + (size_t)NN * 4);      // NN
  int*   rowptr  = deg + NN;                           // NN+1
  int*   cursor  = rowptr + NN + 1;                    // NN
  int*   csr_src = cursor + NN;                        // NE

  hipMemsetAsync(deg, 0, (size_t)NN * sizeof(int), stream);
  {
    const int total = NN * 32 + 4 * (512 * 128 / 4);
    prep_k<<<(total + 255) / 256, 256, 0, stream>>>(
        x, Wq1, Wk1, Wv1, Ws1, x_bf, w1bf, dstp, deg);
  }
  scan_k<<<1, 1024, 0, stream>>>(deg, rowptr, cursor);

  gemm_scatter<<<NGEMM + (NE + 255) / 256, 256, 0, stream>>>(
      x_bf, w1bf, bq1, bk1, bv1, bs1, qbf, k8, v8, h1,
      srcp, dstp, cursor, csr_src);

  attn1<<<NN / 2, 256, 0, stream>>>(qbf, k8, v8, rowptr, csr_src, h1);
  gemm_l2<<<(NN + 63) / 64, 256, 0, stream>>>(
      h1, Wq2, bq2, Wk2, bk2, Wv2, bv2, Ws2, bs2, qkv2, acc2);
  attn2<<<(NN * 16 + 255) / 256, 256, 0, stream>>>(qkv2, rowptr, csr_src, acc2);
  final_k<<<1, 1024, 0, stream>>>(acc2, Wl, bl, (float*)d_out);
}